// Round 6
// baseline (967.950 us; speedup 1.0000x reference)
//
#include <hip/hip_runtime.h>
#include <hip/hip_bf16.h>

#define BIGF 1e30f
#define TC 80
#define TN 512
#define LOG2E 1.44269504088896340736f
#define LN2   0.693147180559945309417f
#define SKIPT 17.0f   // log2-units; gap>17 => fp32 logsumexp correction == 0

#define EXP2F(v) __builtin_amdgcn_exp2f(v)   // v_exp_f32 (2^x)
#define LOG2F(v) __builtin_amdgcn_logf(v)    // v_log_f32 (log2 x)

// ---------------------------------------------------------------------------
// Kernel 1: D[b][n][m] = (||x_n - y_m||^2) * log2e, ROW-MAJOR, float4 stores.
// 128x128 tile, 256 threads, 8x8 micro-tile as 2x2 blocks of float4.
// ---------------------------------------------------------------------------
__global__ __launch_bounds__(256) void pairdist_kernel(
    const float* __restrict__ x, const float* __restrict__ y,
    float* __restrict__ D) {
  const int b  = blockIdx.z;
  const int n0 = blockIdx.x * 128;
  const int m0 = blockIdx.y * 128;

  __shared__ float xs[40][128];
  __shared__ float ys[40][128];
  __shared__ float xxs[128];
  __shared__ float yys[128];

  const float* xb = x + (size_t)b * TC * TN;
  const float* yb = y + (size_t)b * TC * TN;
  const int tid = threadIdx.x;
  const int tm = tid & 15, tn = tid >> 4;

  float acc[2][2][4][4] = {};
  float xxp = 0.f, yyp = 0.f;

  for (int c0 = 0; c0 < TC; c0 += 40) {
    for (int i = tid; i < 40 * 32; i += 256) {
      int c = i >> 5, p = i & 31;
      *(float4*)&xs[c][p * 4] = *(const float4*)&xb[(c0 + c) * TN + n0 + p * 4];
      *(float4*)&ys[c][p * 4] = *(const float4*)&yb[(c0 + c) * TN + m0 + p * 4];
    }
    __syncthreads();

    if (tid < 128) {
      for (int c = 0; c < 40; ++c) { float v = xs[c][tid]; xxp += v * v; }
    } else {
      int t2 = tid - 128;
      for (int c = 0; c < 40; ++c) { float v = ys[c][t2]; yyp += v * v; }
    }

    for (int c = 0; c < 40; ++c) {
      float4 xa0 = *(const float4*)&xs[c][tn * 4];
      float4 xa1 = *(const float4*)&xs[c][tn * 4 + 64];
      float4 ya0 = *(const float4*)&ys[c][tm * 4];
      float4 ya1 = *(const float4*)&ys[c][tm * 4 + 64];
      float xv[2][4] = {{xa0.x, xa0.y, xa0.z, xa0.w}, {xa1.x, xa1.y, xa1.z, xa1.w}};
      float yv[2][4] = {{ya0.x, ya0.y, ya0.z, ya0.w}, {ya1.x, ya1.y, ya1.z, ya1.w}};
#pragma unroll
      for (int g = 0; g < 2; ++g)
#pragma unroll
        for (int h = 0; h < 2; ++h)
#pragma unroll
          for (int a = 0; a < 4; ++a)
#pragma unroll
            for (int q = 0; q < 4; ++q)
              acc[g][h][a][q] += xv[g][a] * yv[h][q];
    }
    __syncthreads();
  }

  if (tid < 128) xxs[tid] = xxp; else yys[tid - 128] = yyp;
  __syncthreads();

  float* Dbase = D + (size_t)b * TN * TN;
#pragma unroll
  for (int g = 0; g < 2; ++g)
#pragma unroll
    for (int a = 0; a < 4; ++a) {
      int n = n0 + tn * 4 + a + g * 64;
      float xxv = xxs[tn * 4 + a + g * 64];
#pragma unroll
      for (int h = 0; h < 2; ++h) {
        float4 o;
        o.x = (xxv + yys[tm * 4 + h * 64 + 0] - 2.f * acc[g][h][a][0]) * LOG2E;
        o.y = (xxv + yys[tm * 4 + h * 64 + 1] - 2.f * acc[g][h][a][1]) * LOG2E;
        o.z = (xxv + yys[tm * 4 + h * 64 + 2] - 2.f * acc[g][h][a][2]) * LOG2E;
        o.w = (xxv + yys[tm * 4 + h * 64 + 3] - 2.f * acc[g][h][a][3]) * LOG2E;
        *(float4*)&Dbase[(size_t)n * TN + m0 + tm * 4 + h * 64] = o;
      }
    }
}

// ---------------------------------------------------------------------------
// Kernel 2: log-domain soft-DTW (R3-proven math), one wave per batch,
// lane l owns rows r = l*8+k. New vs R3: (a) ring-4 prefetch of D (row-major,
// clamped index; invalid cells forced BIG by the proven valid-select);
// (b) skip-softmin: logsumexp correction computed only when any cell's
// second-min is within SKIPT of the min (wave-uniform branch, ~2% of steps).
// Recurrence in base-2 units (D pre-scaled by log2e), output * ln2.
// ---------------------------------------------------------------------------
__global__ __launch_bounds__(64) void sdtw_kernel(
    const float* __restrict__ D, float* __restrict__ out) {
  const int b = blockIdx.x;
  const int l = threadIdx.x;
  const int r0 = l * 8;
  const float* Db = D + (size_t)b * TN * TN + (size_t)r0 * TN;  // Db[k*TN + c]

  float A[8], Bv[8], ring[4][8], sm3[8], sv0[8];
#pragma unroll
  for (int k = 0; k < 8; ++k) { A[k] = BIGF; Bv[k] = BIGF; }

  float u0 = (l == 0) ? 0.f : BIGF;  // R_0 boundary above lane's first row
  int e = -r0;                       // e = o - r0; cell k valid iff (unsigned)(e-k)<=511

#define PREF(S, OO)                                                       \
  {                                                                       \
    int cb_ = (OO) - r0;                                                  \
    _Pragma("unroll")                                                     \
    for (int k = 0; k < 8; ++k) {                                         \
      int c_ = cb_ - k;                                                   \
      c_ = c_ < 0 ? 0 : (c_ > TN - 1 ? TN - 1 : c_);                      \
      ring[S][k] = Db[k * TN + c_];                                       \
    }                                                                     \
  }

#define STEP(O2, O1, S, OO)                                               \
  {                                                                       \
    float u1 = __shfl_up(O1[7], 1, 64);                                   \
    if (l == 0) u1 = BIGF;                                                \
    int need = 0;                                                         \
    _Pragma("unroll")                                                     \
    for (int k = 7; k >= 0; --k) {                                        \
      float rr0 = k ? O2[k - 1] : u0;                                     \
      float rr1 = k ? O1[k - 1] : u1;                                     \
      float rr2 = O1[k];                                                  \
      float m3 = fminf(fminf(rr0, rr1), rr2);                             \
      float sec = __builtin_amdgcn_fmed3f(rr0, rr1, rr2);                 \
      need |= (sec < m3 + SKIPT);                                         \
      sv0[k] = rr0;                                                       \
      sm3[k] = m3;                                                        \
    }                                                                     \
    if (__any(need)) {                                                    \
      _Pragma("unroll")                                                   \
      for (int k = 7; k >= 0; --k) {                                      \
        float m3 = sm3[k];                                                \
        float rr1 = k ? O1[k - 1] : u1;                                   \
        float s = EXP2F(m3 - sv0[k]) + EXP2F(m3 - rr1) + EXP2F(m3 - O1[k]);\
        sm3[k] = m3 - LOG2F(s);                                           \
      }                                                                   \
    }                                                                     \
    PREF(S, (OO) + 4)                                                     \
    _Pragma("unroll")                                                     \
    for (int k = 7; k >= 0; --k) {                                        \
      O2[k] = ((unsigned)(e - k) <= (unsigned)(TN - 1))                   \
                  ? (ring[S][k] + sm3[k]) : BIGF;                         \
    }                                                                     \
    u0 = u1;                                                              \
    ++e;                                                                  \
  }

  PREF(0, 0) PREF(1, 1) PREF(2, 2) PREF(3, 3)

  int o = 0;
  for (int it = 0; it < 255; ++it) {
    STEP(A, Bv, 0, o)
    STEP(Bv, A, 1, o + 1)
    STEP(A, Bv, 2, o + 2)
    STEP(Bv, A, 3, o + 3)
    o += 4;
  }
  // o = 1020, 1021, 1022
  STEP(A, Bv, 0, o)
  STEP(Bv, A, 1, o + 1)
  STEP(A, Bv, 2, o + 2)
#undef STEP
#undef PREF

  // corner (511,511): o=1022, lane 63, k=7; convert log2 -> nat units
  if (l == 63) out[b] = A[7] * LN2;
}

extern "C" void kernel_launch(void* const* d_in, const int* in_sizes, int n_in,
                              void* d_out, int out_size, void* d_ws, size_t ws_size,
                              hipStream_t stream) {
  const float* x = (const float*)d_in[0];
  const float* y = (const float*)d_in[1];
  float* out = (float*)d_out;
  float* D = (float*)d_ws;  // 32*512*512*4 = 33.5 MB

  dim3 g1(TN / 128, TN / 128, 32);
  pairdist_kernel<<<g1, 256, 0, stream>>>(x, y, D);
  sdtw_kernel<<<32, 64, 0, stream>>>(D, out);
}